// Round 9
// baseline (170.197 us; speedup 1.0000x reference)
//
#include <hip/hip_runtime.h>
#include <math.h>

#define NNODES 50000
#define NEDGES 800000
#define SCAN_NB ((NNODES + 255) / 256)   // 196
#define L0ROWS 64
#define SC_CHUNKS 128                    // scatter: edge chunks (x8 buckets = 1024 blocks)
#define ROWS_PER_BUCKET 6250             // 50000/8

// butterfly reductions: result valid in ALL lanes
__device__ inline float bsum64(float v) {
    #pragma unroll
    for (int off = 1; off < 64; off <<= 1) v += __shfl_xor(v, off, 64);
    return v;
}

// pack two f32 -> 2x bf16 (RNE) in one uint
__device__ inline unsigned packbf2(float a, float b) {
    unsigned ua = __float_as_uint(a);
    unsigned ub = __float_as_uint(b);
    ua = (ua + 0x7fffu + ((ua >> 16) & 1u)) >> 16;
    ub = (ub + 0x7fffu + ((ub >> 16) & 1u)) >> 16;
    return ua | (ub << 16);
}
__device__ inline float bflo(unsigned u) { return __uint_as_float(u << 16); }
__device__ inline float bfhi(unsigned u) { return __uint_as_float(u & 0xffff0000u); }

// ---- zero the degree counters ----
__global__ void k_zero(int* __restrict__ deg) {
    int i = blockIdx.x * blockDim.x + threadIdx.x;
    if (i < NNODES) deg[i] = 0;
}

// ---- CSR build: histogram + per-edge local rank ----
__global__ __launch_bounds__(256) void k_hist(const int* __restrict__ ei,
                                              int* __restrict__ deg,
                                              int* __restrict__ erank) {
    int e = blockIdx.x * blockDim.x + threadIdx.x;
    if (e >= NEDGES) return;
    erank[e] = atomicAdd(&deg[ei[e]], 1);
}

// ---- scan pass 1 ----
__global__ __launch_bounds__(256) void k_scan1(const int* __restrict__ deg,
                                               int* __restrict__ rowptr,
                                               int* __restrict__ bsum) {
    __shared__ int sh[256];
    int t = threadIdx.x;
    int idx = blockIdx.x * 256 + t;
    int v = (idx < NNODES) ? deg[idx] : 0;
    sh[t] = v;
    __syncthreads();
    #pragma unroll
    for (int off = 1; off < 256; off <<= 1) {
        int u = (t >= off) ? sh[t - off] : 0;
        __syncthreads();
        sh[t] += u;
        __syncthreads();
    }
    if (idx < NNODES) rowptr[idx] = sh[t] - v;
    if (t == 255) bsum[blockIdx.x] = sh[255];
}

// ---- scan pass 2 ----
__global__ __launch_bounds__(256) void k_scan2(const int* __restrict__ bsum,
                                               int* __restrict__ boff) {
    __shared__ int sh[256];
    int t = threadIdx.x;
    int v = (t < SCAN_NB) ? bsum[t] : 0;
    sh[t] = v;
    __syncthreads();
    #pragma unroll
    for (int off = 1; off < 256; off <<= 1) {
        int u = (t >= off) ? sh[t - off] : 0;
        __syncthreads();
        sh[t] += u;
        __syncthreads();
    }
    if (t < SCAN_NB) boff[t] = sh[t] - v;
}

// ---- scan pass 3 ----
__global__ __launch_bounds__(256) void k_scan3(int* __restrict__ rowptr,
                                               const int* __restrict__ boff) {
    int idx = blockIdx.x * 256 + threadIdx.x;
    if (idx < NNODES) rowptr[idx] += boff[blockIdx.x];
    if (idx == 0) rowptr[NNODES] = NEDGES;
}

// ---- CSR scatter, XCD-bucketed: block (chunk=b>>3, bucket=b&7) writes only
//      rows in [bucket*6250,(bucket+1)*6250) so each ecol cacheline is dirtied
//      from (likely) one XCD's L2 -> writebacks merge. Correct for ANY mapping. ----
__global__ __launch_bounds__(256) void k_scatter(const int* __restrict__ ei,
                                                 const int* __restrict__ rowptr,
                                                 const int* __restrict__ erank,
                                                 int* __restrict__ ecol) {
    int bucket = blockIdx.x & 7;
    int chunk = blockIdx.x >> 3;
    const int per = NEDGES / SC_CHUNKS;    // 6250
    int beg = chunk * per;
    int end = beg + per;
    for (int e = beg + threadIdx.x; e < end; e += 256) {
        int row = ei[e];
        if (row / ROWS_PER_BUCKET == bucket) {
            ecol[rowptr[row] + erank[e]] = ei[NEDGES + e];
        }
    }
}

// ---- layer 0 node work: fp32 GEMM, 64 rows/block, 4x8 per thread, W prefetch ----
// thread (rg=t>>4, jg=t&15): rows rg*4..+3, cols jg*8..+7; head = jg>>3
__global__ __launch_bounds__(256) void k_l0node(const float* __restrict__ x,
                                                const float* __restrict__ W,
                                                const float* __restrict__ attn0,
                                                float* __restrict__ ar,
                                                float* __restrict__ ac,
                                                unsigned* __restrict__ h0b) {
    __shared__ float xs[L0ROWS * 128];   // 32 KB
    int n0 = blockIdx.x * L0ROWS;
    int t = threadIdx.x;
    for (int i = t; i < L0ROWS * 32; i += 256) {
        int r = i >> 5, c4 = i & 31;
        int n = n0 + r;
        float4 v = (n < NNODES) ? *(const float4*)&x[n * 128 + c4 * 4]
                                : make_float4(0.f, 0.f, 0.f, 0.f);
        *(float4*)&xs[r * 128 + c4 * 4] = v;
    }
    __syncthreads();
    int rg = t >> 4;     // 0..15 -> rows rg*4..+3
    int jg = t & 15;     // 0..15 -> cols jg*8..+7
    float acc[4][8];
    #pragma unroll
    for (int i = 0; i < 4; i++)
        #pragma unroll
        for (int j = 0; j < 8; j++) acc[i][j] = 0.f;

    float4 bc[4][2];
    #pragma unroll
    for (int kk = 0; kk < 4; kk++) {
        bc[kk][0] = *(const float4*)&W[kk * 128 + jg * 8];
        bc[kk][1] = *(const float4*)&W[kk * 128 + jg * 8 + 4];
    }

    for (int k = 0; k < 128; k += 4) {
        float4 av[4];
        #pragma unroll
        for (int rr = 0; rr < 4; rr++)
            av[rr] = *(const float4*)&xs[(rg * 4 + rr) * 128 + k];   // broadcast, conflict-free
        float4 bn[4][2];
        int k2 = (k + 4) & 127;
        #pragma unroll
        for (int kk = 0; kk < 4; kk++) {
            bn[kk][0] = *(const float4*)&W[(k2 + kk) * 128 + jg * 8];
            bn[kk][1] = *(const float4*)&W[(k2 + kk) * 128 + jg * 8 + 4];
        }
        #pragma unroll
        for (int kk = 0; kk < 4; kk++) {
            #pragma unroll
            for (int rr = 0; rr < 4; rr++) {
                float a = ((const float*)&av[rr])[kk];
                acc[rr][0] += a * bc[kk][0].x;
                acc[rr][1] += a * bc[kk][0].y;
                acc[rr][2] += a * bc[kk][0].z;
                acc[rr][3] += a * bc[kk][0].w;
                acc[rr][4] += a * bc[kk][1].x;
                acc[rr][5] += a * bc[kk][1].y;
                acc[rr][6] += a * bc[kk][1].z;
                acc[rr][7] += a * bc[kk][1].w;
            }
        }
        #pragma unroll
        for (int kk = 0; kk < 4; kk++) { bc[kk][0] = bn[kk][0]; bc[kk][1] = bn[kk][1]; }
    }

    // attention dots: thread's 8 cols are one head's channels (jg>>3 = head)
    int head = jg >> 3;
    int chb = (jg & 7) * 8;
    float wr[8], wc[8];
    *(float4*)&wr[0] = *(const float4*)&attn0[head * 128 + chb];
    *(float4*)&wr[4] = *(const float4*)&attn0[head * 128 + chb + 4];
    *(float4*)&wc[0] = *(const float4*)&attn0[head * 128 + 64 + chb];
    *(float4*)&wc[4] = *(const float4*)&attn0[head * 128 + 64 + chb + 4];
    #pragma unroll
    for (int rr = 0; rr < 4; rr++) {
        float pr = 0.f, pc = 0.f;
        #pragma unroll
        for (int cc = 0; cc < 8; cc++) {
            pr += acc[rr][cc] * wr[cc];
            pc += acc[rr][cc] * wc[cc];
        }
        #pragma unroll
        for (int off = 1; off < 8; off <<= 1) {
            pr += __shfl_xor(pr, off, 64);
            pc += __shfl_xor(pc, off, 64);
        }
        int n = n0 + rg * 4 + rr;
        if ((jg & 7) == 0 && n < NNODES) {
            ar[n * 2 + head] = pr;
            ac[n * 2 + head] = pc;
        }
    }

    // bf16 pack via LDS re-stage
    __syncthreads();
    #pragma unroll
    for (int rr = 0; rr < 4; rr++) {
        *(float4*)&xs[(rg * 4 + rr) * 128 + jg * 8]     = *(float4*)&acc[rr][0];
        *(float4*)&xs[(rg * 4 + rr) * 128 + jg * 8 + 4] = *(float4*)&acc[rr][4];
    }
    __syncthreads();
    for (int i = t; i < L0ROWS * 16; i += 256) {
        int r = i >> 4, cb = (i & 15) * 4;
        int n = n0 + r;
        if (n < NNODES) {
            uint4 u;
            u.x = packbf2(xs[r * 128 + cb + 0], xs[r * 128 + 64 + cb + 0]);
            u.y = packbf2(xs[r * 128 + cb + 1], xs[r * 128 + 64 + cb + 1]);
            u.z = packbf2(xs[r * 128 + cb + 2], xs[r * 128 + 64 + cb + 2]);
            u.w = packbf2(xs[r * 128 + cb + 3], xs[r * 128 + 64 + cb + 3]);
            *(uint4*)(h0b + n * 64 + cb) = u;
        }
    }
}

// ---- layer 0 edge work: softmax weights (no max-subtract) + aggregation
//      + relu + W1 transform -> h1[N,2].  One wave per node. ----
__global__ __launch_bounds__(256) void k_l0edge(const int* __restrict__ rowptr,
                                                const int* __restrict__ ecol,
                                                const float* __restrict__ ar,
                                                const float* __restrict__ ac,
                                                const unsigned* __restrict__ h0b,
                                                const float* __restrict__ W1,
                                                float* __restrict__ h1) {
    int w = threadIdx.x >> 6, lane = threadIdx.x & 63;
    int n = blockIdx.x * 4 + w;
    if (n >= NNODES) return;
    int beg = rowptr[n];
    int deg = rowptr[n + 1] - beg;
    float arn0 = ar[n * 2], arn1 = ar[n * 2 + 1];
    int esub = lane >> 4;          // which of 4 edges in flight
    int c16 = lane & 15;           // channel group (4 channels)
    float accA[4] = {0.f, 0.f, 0.f, 0.f};   // head 0
    float accB[4] = {0.f, 0.f, 0.f, 0.f};   // head 1
    float s0t = 0.f, s1t = 0.f;
    for (int wb = 0; wb < deg; wb += 64) {
        int cnt = deg - wb; if (cnt > 64) cnt = 64;
        float p0 = 0.f, p1 = 0.f; int colr = 0;
        if (lane < cnt) {
            colr = ecol[beg + wb + lane];
            float2 acv = ((const float2*)ac)[colr];
            float a0 = arn0 + acv.x, a1 = arn1 + acv.y;
            a0 = a0 > 0.f ? a0 : 0.2f * a0;
            a1 = a1 > 0.f ? a1 : 0.2f * a1;
            p0 = __expf(a0); p1 = __expf(a1);
            s0t += p0; s1t += p1;
        }
        int tmax = (cnt + 3) >> 2;
        for (int tt = 0; tt < tmax; tt++) {
            int i4 = tt * 4 + esub;
            int colx = __shfl(colr, i4, 64);
            float q0 = __shfl(p0, i4, 64);
            float q1 = __shfl(p1, i4, 64);
            if (i4 < cnt) {
                const uint4 u = *(const uint4*)(h0b + colx * 64 + c16 * 4);
                accA[0] += q0 * bflo(u.x); accB[0] += q1 * bfhi(u.x);
                accA[1] += q0 * bflo(u.y); accB[1] += q1 * bfhi(u.y);
                accA[2] += q0 * bflo(u.z); accB[2] += q1 * bfhi(u.z);
                accA[3] += q0 * bflo(u.w); accB[3] += q1 * bfhi(u.w);
            }
        }
    }
    float s0 = bsum64(s0t), s1 = bsum64(s1t);
    #pragma unroll
    for (int jj = 0; jj < 4; jj++) {
        accA[jj] += __shfl_xor(accA[jj], 16, 64);
        accA[jj] += __shfl_xor(accA[jj], 32, 64);
        accB[jj] += __shfl_xor(accB[jj], 16, 64);
        accB[jj] += __shfl_xor(accB[jj], 32, 64);
    }
    float si0 = deg ? 0.5f / s0 : 0.f;
    float si1 = deg ? 0.5f / s1 : 0.f;
    float pA = 0.f, pB = 0.f;
    #pragma unroll
    for (int jj = 0; jj < 4; jj++) {
        float o = si0 * accA[jj] + si1 * accB[jj];
        o = o > 0.f ? o : 0.f;   // relu
        float2 wv = ((const float2*)W1)[c16 * 4 + jj];
        pA += o * wv.x; pB += o * wv.y;
    }
    #pragma unroll
    for (int off = 1; off < 16; off <<= 1) {
        pA += __shfl_xor(pA, off, 64);
        pB += __shfl_xor(pB, off, 64);
    }
    if (lane == 0) { h1[n * 2] = pA; h1[n * 2 + 1] = pB; }
}

// ---- layer 1 fused: wave per node, lane = edge, plain (no-max) softmax ----
__global__ __launch_bounds__(256) void k_fused1(const int* __restrict__ rowptr,
                                                const int* __restrict__ ecol,
                                                const float* __restrict__ h1,
                                                const float* __restrict__ attn1,
                                                float* __restrict__ dout) {
    int w = threadIdx.x >> 6, lane = threadIdx.x & 63;
    int n = blockIdx.x * 4 + w;
    if (n >= NNODES) return;
    int beg = rowptr[n], end = rowptr[n + 1];
    if (beg == end) { if (lane == 0) dout[n] = 0.f; return; }
    float w01 = attn1[1], w11 = attn1[3];
    float base0 = attn1[0] * h1[n * 2];
    float base1 = attn1[2] * h1[n * 2 + 1];
    float s0 = 0.f, s1 = 0.f, acc0 = 0.f, acc1 = 0.f;
    for (int i = beg + lane; i < end; i += 64) {
        int col = ecol[i];
        float2 v = ((const float2*)h1)[col];
        float a0 = base0 + w01 * v.x;
        float a1 = base1 + w11 * v.y;
        a0 = a0 > 0.f ? a0 : 0.2f * a0;
        a1 = a1 > 0.f ? a1 : 0.2f * a1;
        float p0 = __expf(a0), p1 = __expf(a1);
        s0 += p0; acc0 += p0 * v.x;
        s1 += p1; acc1 += p1 * v.y;
    }
    s0 = bsum64(s0); s1 = bsum64(s1);
    acc0 = bsum64(acc0); acc1 = bsum64(acc1);
    if (lane == 0) dout[n] = 0.5f * (acc0 / s0 + acc1 / s1);
}

extern "C" void kernel_launch(void* const* d_in, const int* in_sizes, int n_in,
                              void* d_out, int out_size, void* d_ws, size_t ws_size,
                              hipStream_t stream) {
    const float* x     = (const float*)d_in[0];
    const int*   ei    = (const int*)d_in[1];
    const float* W0    = (const float*)d_in[2];
    const float* attn0 = (const float*)d_in[3];
    const float* W1    = (const float*)d_in[4];
    const float* attn1 = (const float*)d_in[5];
    float* dout = (float*)d_out;

    float* ws = (float*)d_ws;
    float*    ar     = ws;                           // N*2
    float*    ac     = ar + NNODES * 2;              // N*2
    float*    h1     = ac + NNODES * 2;              // N*2
    unsigned* h0b    = (unsigned*)(h1 + NNODES * 2); // N*64
    int*      deg    = (int*)(h0b + NNODES * 64);    // N
    int*      rowptr = deg + NNODES;                 // N+1
    int*      erank  = rowptr + NNODES + 1;          // E
    int*      bsum   = erank + NEDGES;               // SCAN_NB
    int*      boff   = bsum + SCAN_NB;               // SCAN_NB
    int*      ecol   = boff + SCAN_NB;               // E

    // CSR build
    k_zero<<<(NNODES + 255) / 256, 256, 0, stream>>>(deg);
    k_hist<<<(NEDGES + 255) / 256, 256, 0, stream>>>(ei, deg, erank);
    k_scan1<<<SCAN_NB, 256, 0, stream>>>(deg, rowptr, bsum);
    k_scan2<<<1, 256, 0, stream>>>(bsum, boff);
    k_scan3<<<SCAN_NB, 256, 0, stream>>>(rowptr, boff);
    k_scatter<<<8 * SC_CHUNKS, 256, 0, stream>>>(ei, rowptr, erank, ecol);

    // layer 0
    k_l0node<<<(NNODES + L0ROWS - 1) / L0ROWS, 256, 0, stream>>>(x, W0, attn0, ar, ac, h0b);
    k_l0edge<<<(NNODES + 3) / 4, 256, 0, stream>>>(rowptr, ecol, ar, ac, h0b, W1, h1);

    // layer 1
    k_fused1<<<(NNODES + 3) / 4, 256, 0, stream>>>(rowptr, ecol, h1, attn1, dout);
}

// Round 10
// 156.872 us; speedup vs baseline: 1.0849x; 1.0849x over previous
//
#include <hip/hip_runtime.h>
#include <math.h>

#define NNODES 50000
#define NEDGES 800000
#define SCAN_NB ((NNODES + 255) / 256)   // 196
#define L0ROWS 64
#define XSS 132                          // padded LDS row stride (floats): breaks 4-way bank conflict

// butterfly reductions: result valid in ALL lanes
__device__ inline float bsum64(float v) {
    #pragma unroll
    for (int off = 1; off < 64; off <<= 1) v += __shfl_xor(v, off, 64);
    return v;
}

// pack two f32 -> 2x bf16 (RNE) in one uint
__device__ inline unsigned packbf2(float a, float b) {
    unsigned ua = __float_as_uint(a);
    unsigned ub = __float_as_uint(b);
    ua = (ua + 0x7fffu + ((ua >> 16) & 1u)) >> 16;
    ub = (ub + 0x7fffu + ((ub >> 16) & 1u)) >> 16;
    return ua | (ub << 16);
}
__device__ inline float bflo(unsigned u) { return __uint_as_float(u << 16); }
__device__ inline float bfhi(unsigned u) { return __uint_as_float(u & 0xffff0000u); }

// ---- zero the degree counters ----
__global__ void k_zero(int* __restrict__ deg) {
    int i = blockIdx.x * blockDim.x + threadIdx.x;
    if (i < NNODES) deg[i] = 0;
}

// ---- CSR build: histogram + per-edge local rank ----
__global__ __launch_bounds__(256) void k_hist(const int* __restrict__ ei,
                                              int* __restrict__ deg,
                                              int* __restrict__ erank) {
    int e = blockIdx.x * blockDim.x + threadIdx.x;
    if (e >= NEDGES) return;
    erank[e] = atomicAdd(&deg[ei[e]], 1);
}

// ---- scan pass 1 ----
__global__ __launch_bounds__(256) void k_scan1(const int* __restrict__ deg,
                                               int* __restrict__ rowptr,
                                               int* __restrict__ bsum) {
    __shared__ int sh[256];
    int t = threadIdx.x;
    int idx = blockIdx.x * 256 + t;
    int v = (idx < NNODES) ? deg[idx] : 0;
    sh[t] = v;
    __syncthreads();
    #pragma unroll
    for (int off = 1; off < 256; off <<= 1) {
        int u = (t >= off) ? sh[t - off] : 0;
        __syncthreads();
        sh[t] += u;
        __syncthreads();
    }
    if (idx < NNODES) rowptr[idx] = sh[t] - v;
    if (t == 255) bsum[blockIdx.x] = sh[255];
}

// ---- scan pass 2 ----
__global__ __launch_bounds__(256) void k_scan2(const int* __restrict__ bsum,
                                               int* __restrict__ boff) {
    __shared__ int sh[256];
    int t = threadIdx.x;
    int v = (t < SCAN_NB) ? bsum[t] : 0;
    sh[t] = v;
    __syncthreads();
    #pragma unroll
    for (int off = 1; off < 256; off <<= 1) {
        int u = (t >= off) ? sh[t - off] : 0;
        __syncthreads();
        sh[t] += u;
        __syncthreads();
    }
    if (t < SCAN_NB) boff[t] = sh[t] - v;
}

// ---- scan pass 3 ----
__global__ __launch_bounds__(256) void k_scan3(int* __restrict__ rowptr,
                                               const int* __restrict__ boff) {
    int idx = blockIdx.x * 256 + threadIdx.x;
    if (idx < NNODES) rowptr[idx] += boff[blockIdx.x];
    if (idx == 0) rowptr[NNODES] = NEDGES;
}

// ---- CSR build: simple scatter (no atomic; rank precomputed) ----
__global__ __launch_bounds__(256) void k_scatter(const int* __restrict__ ei,
                                                 const int* __restrict__ rowptr,
                                                 const int* __restrict__ erank,
                                                 int* __restrict__ ecol) {
    int e = blockIdx.x * blockDim.x + threadIdx.x;
    if (e >= NEDGES) return;
    int row = ei[e], col = ei[NEDGES + e];
    ecol[rowptr[row] + erank[e]] = col;
}

// ---- layer 0 node work: fp32 GEMM, 64 rows/block, 4x8 per thread, padded LDS ----
// thread (rg=t>>4, jg=t&15): rows rg*4..+3, cols jg*8..+7; head = jg>>3
__global__ __launch_bounds__(256) void k_l0node(const float* __restrict__ x,
                                                const float* __restrict__ W,
                                                const float* __restrict__ attn0,
                                                float* __restrict__ ar,
                                                float* __restrict__ ac,
                                                unsigned* __restrict__ h0b) {
    __shared__ float xs[L0ROWS * XSS];   // 33 KB, stride 132 breaks bank conflicts
    int n0 = blockIdx.x * L0ROWS;
    int t = threadIdx.x;
    for (int i = t; i < L0ROWS * 32; i += 256) {
        int r = i >> 5, c4 = i & 31;
        int n = n0 + r;
        float4 v = (n < NNODES) ? *(const float4*)&x[n * 128 + c4 * 4]
                                : make_float4(0.f, 0.f, 0.f, 0.f);
        *(float4*)&xs[r * XSS + c4 * 4] = v;
    }
    __syncthreads();
    int rg = t >> 4;     // 0..15 -> rows rg*4..+3
    int jg = t & 15;     // 0..15 -> cols jg*8..+7
    float acc[4][8];
    #pragma unroll
    for (int i = 0; i < 4; i++)
        #pragma unroll
        for (int j = 0; j < 8; j++) acc[i][j] = 0.f;

    float4 bc[4][2];
    #pragma unroll
    for (int kk = 0; kk < 4; kk++) {
        bc[kk][0] = *(const float4*)&W[kk * 128 + jg * 8];
        bc[kk][1] = *(const float4*)&W[kk * 128 + jg * 8 + 4];
    }

    for (int k = 0; k < 128; k += 4) {
        float4 av[4];
        #pragma unroll
        for (int rr = 0; rr < 4; rr++)
            av[rr] = *(const float4*)&xs[(rg * 4 + rr) * XSS + k];   // 2-way max, free
        float4 bn[4][2];
        int k2 = (k + 4) & 127;
        #pragma unroll
        for (int kk = 0; kk < 4; kk++) {
            bn[kk][0] = *(const float4*)&W[(k2 + kk) * 128 + jg * 8];
            bn[kk][1] = *(const float4*)&W[(k2 + kk) * 128 + jg * 8 + 4];
        }
        #pragma unroll
        for (int kk = 0; kk < 4; kk++) {
            #pragma unroll
            for (int rr = 0; rr < 4; rr++) {
                float a = ((const float*)&av[rr])[kk];
                acc[rr][0] += a * bc[kk][0].x;
                acc[rr][1] += a * bc[kk][0].y;
                acc[rr][2] += a * bc[kk][0].z;
                acc[rr][3] += a * bc[kk][0].w;
                acc[rr][4] += a * bc[kk][1].x;
                acc[rr][5] += a * bc[kk][1].y;
                acc[rr][6] += a * bc[kk][1].z;
                acc[rr][7] += a * bc[kk][1].w;
            }
        }
        #pragma unroll
        for (int kk = 0; kk < 4; kk++) { bc[kk][0] = bn[kk][0]; bc[kk][1] = bn[kk][1]; }
    }

    // attention dots: thread's 8 cols belong to one head (jg>>3)
    int head = jg >> 3;
    int chb = (jg & 7) * 8;
    float wr[8], wc[8];
    *(float4*)&wr[0] = *(const float4*)&attn0[head * 128 + chb];
    *(float4*)&wr[4] = *(const float4*)&attn0[head * 128 + chb + 4];
    *(float4*)&wc[0] = *(const float4*)&attn0[head * 128 + 64 + chb];
    *(float4*)&wc[4] = *(const float4*)&attn0[head * 128 + 64 + chb + 4];
    #pragma unroll
    for (int rr = 0; rr < 4; rr++) {
        float pr = 0.f, pc = 0.f;
        #pragma unroll
        for (int cc = 0; cc < 8; cc++) {
            pr += acc[rr][cc] * wr[cc];
            pc += acc[rr][cc] * wc[cc];
        }
        #pragma unroll
        for (int off = 1; off < 8; off <<= 1) {
            pr += __shfl_xor(pr, off, 64);
            pc += __shfl_xor(pc, off, 64);
        }
        int n = n0 + rg * 4 + rr;
        if ((jg & 7) == 0 && n < NNODES) {
            ar[n * 2 + head] = pr;
            ac[n * 2 + head] = pc;
        }
    }

    // bf16 pack via LDS re-stage
    __syncthreads();
    #pragma unroll
    for (int rr = 0; rr < 4; rr++) {
        *(float4*)&xs[(rg * 4 + rr) * XSS + jg * 8]     = *(float4*)&acc[rr][0];
        *(float4*)&xs[(rg * 4 + rr) * XSS + jg * 8 + 4] = *(float4*)&acc[rr][4];
    }
    __syncthreads();
    for (int i = t; i < L0ROWS * 16; i += 256) {
        int r = i >> 4, cb = (i & 15) * 4;
        int n = n0 + r;
        if (n < NNODES) {
            uint4 u;
            u.x = packbf2(xs[r * XSS + cb + 0], xs[r * XSS + 64 + cb + 0]);
            u.y = packbf2(xs[r * XSS + cb + 1], xs[r * XSS + 64 + cb + 1]);
            u.z = packbf2(xs[r * XSS + cb + 2], xs[r * XSS + 64 + cb + 2]);
            u.w = packbf2(xs[r * XSS + cb + 3], xs[r * XSS + 64 + cb + 3]);
            *(uint4*)(h0b + n * 64 + cb) = u;
        }
    }
}

// ---- layer 0 edge work: softmax weights (no max-subtract) + aggregation
//      + relu + W1 transform -> h1[N,2].  One wave per node. ----
__global__ __launch_bounds__(256) void k_l0edge(const int* __restrict__ rowptr,
                                                const int* __restrict__ ecol,
                                                const float* __restrict__ ar,
                                                const float* __restrict__ ac,
                                                const unsigned* __restrict__ h0b,
                                                const float* __restrict__ W1,
                                                float* __restrict__ h1) {
    int w = threadIdx.x >> 6, lane = threadIdx.x & 63;
    int n = blockIdx.x * 4 + w;
    if (n >= NNODES) return;
    int beg = rowptr[n];
    int deg = rowptr[n + 1] - beg;
    float arn0 = ar[n * 2], arn1 = ar[n * 2 + 1];
    int esub = lane >> 4;          // which of 4 edges in flight
    int c16 = lane & 15;           // channel group (4 channels)
    float accA[4] = {0.f, 0.f, 0.f, 0.f};   // head 0
    float accB[4] = {0.f, 0.f, 0.f, 0.f};   // head 1
    float s0t = 0.f, s1t = 0.f;
    for (int wb = 0; wb < deg; wb += 64) {
        int cnt = deg - wb; if (cnt > 64) cnt = 64;
        float p0 = 0.f, p1 = 0.f; int colr = 0;
        if (lane < cnt) {
            colr = ecol[beg + wb + lane];
            float2 acv = ((const float2*)ac)[colr];
            float a0 = arn0 + acv.x, a1 = arn1 + acv.y;
            a0 = a0 > 0.f ? a0 : 0.2f * a0;
            a1 = a1 > 0.f ? a1 : 0.2f * a1;
            p0 = __expf(a0); p1 = __expf(a1);
            s0t += p0; s1t += p1;
        }
        int tmax = (cnt + 3) >> 2;
        for (int tt = 0; tt < tmax; tt++) {
            int i4 = tt * 4 + esub;
            int colx = __shfl(colr, i4, 64);
            float q0 = __shfl(p0, i4, 64);
            float q1 = __shfl(p1, i4, 64);
            if (i4 < cnt) {
                const uint4 u = *(const uint4*)(h0b + colx * 64 + c16 * 4);
                accA[0] += q0 * bflo(u.x); accB[0] += q1 * bfhi(u.x);
                accA[1] += q0 * bflo(u.y); accB[1] += q1 * bfhi(u.y);
                accA[2] += q0 * bflo(u.z); accB[2] += q1 * bfhi(u.z);
                accA[3] += q0 * bflo(u.w); accB[3] += q1 * bfhi(u.w);
            }
        }
    }
    float s0 = bsum64(s0t), s1 = bsum64(s1t);
    #pragma unroll
    for (int jj = 0; jj < 4; jj++) {
        accA[jj] += __shfl_xor(accA[jj], 16, 64);
        accA[jj] += __shfl_xor(accA[jj], 32, 64);
        accB[jj] += __shfl_xor(accB[jj], 16, 64);
        accB[jj] += __shfl_xor(accB[jj], 32, 64);
    }
    float si0 = deg ? 0.5f / s0 : 0.f;
    float si1 = deg ? 0.5f / s1 : 0.f;
    float pA = 0.f, pB = 0.f;
    #pragma unroll
    for (int jj = 0; jj < 4; jj++) {
        float o = si0 * accA[jj] + si1 * accB[jj];
        o = o > 0.f ? o : 0.f;   // relu
        float2 wv = ((const float2*)W1)[c16 * 4 + jj];
        pA += o * wv.x; pB += o * wv.y;
    }
    #pragma unroll
    for (int off = 1; off < 16; off <<= 1) {
        pA += __shfl_xor(pA, off, 64);
        pB += __shfl_xor(pB, off, 64);
    }
    if (lane == 0) { h1[n * 2] = pA; h1[n * 2 + 1] = pB; }
}

// ---- layer 1 fused: wave per node, lane = edge, plain (no-max) softmax ----
__global__ __launch_bounds__(256) void k_fused1(const int* __restrict__ rowptr,
                                                const int* __restrict__ ecol,
                                                const float* __restrict__ h1,
                                                const float* __restrict__ attn1,
                                                float* __restrict__ dout) {
    int w = threadIdx.x >> 6, lane = threadIdx.x & 63;
    int n = blockIdx.x * 4 + w;
    if (n >= NNODES) return;
    int beg = rowptr[n], end = rowptr[n + 1];
    if (beg == end) { if (lane == 0) dout[n] = 0.f; return; }
    float w01 = attn1[1], w11 = attn1[3];
    float base0 = attn1[0] * h1[n * 2];
    float base1 = attn1[2] * h1[n * 2 + 1];
    float s0 = 0.f, s1 = 0.f, acc0 = 0.f, acc1 = 0.f;
    for (int i = beg + lane; i < end; i += 64) {
        int col = ecol[i];
        float2 v = ((const float2*)h1)[col];
        float a0 = base0 + w01 * v.x;
        float a1 = base1 + w11 * v.y;
        a0 = a0 > 0.f ? a0 : 0.2f * a0;
        a1 = a1 > 0.f ? a1 : 0.2f * a1;
        float p0 = __expf(a0), p1 = __expf(a1);
        s0 += p0; acc0 += p0 * v.x;
        s1 += p1; acc1 += p1 * v.y;
    }
    s0 = bsum64(s0); s1 = bsum64(s1);
    acc0 = bsum64(acc0); acc1 = bsum64(acc1);
    if (lane == 0) dout[n] = 0.5f * (acc0 / s0 + acc1 / s1);
}

extern "C" void kernel_launch(void* const* d_in, const int* in_sizes, int n_in,
                              void* d_out, int out_size, void* d_ws, size_t ws_size,
                              hipStream_t stream) {
    const float* x     = (const float*)d_in[0];
    const int*   ei    = (const int*)d_in[1];
    const float* W0    = (const float*)d_in[2];
    const float* attn0 = (const float*)d_in[3];
    const float* W1    = (const float*)d_in[4];
    const float* attn1 = (const float*)d_in[5];
    float* dout = (float*)d_out;

    float* ws = (float*)d_ws;
    float*    ar     = ws;                           // N*2
    float*    ac     = ar + NNODES * 2;              // N*2
    float*    h1     = ac + NNODES * 2;              // N*2
    unsigned* h0b    = (unsigned*)(h1 + NNODES * 2); // N*64
    int*      deg    = (int*)(h0b + NNODES * 64);    // N
    int*      rowptr = deg + NNODES;                 // N+1
    int*      erank  = rowptr + NNODES + 1;          // E
    int*      bsum   = erank + NEDGES;               // SCAN_NB
    int*      boff   = bsum + SCAN_NB;               // SCAN_NB
    int*      ecol   = boff + SCAN_NB;               // E

    // CSR build
    k_zero<<<(NNODES + 255) / 256, 256, 0, stream>>>(deg);
    k_hist<<<(NEDGES + 255) / 256, 256, 0, stream>>>(ei, deg, erank);
    k_scan1<<<SCAN_NB, 256, 0, stream>>>(deg, rowptr, bsum);
    k_scan2<<<1, 256, 0, stream>>>(bsum, boff);
    k_scan3<<<SCAN_NB, 256, 0, stream>>>(rowptr, boff);
    k_scatter<<<(NEDGES + 255) / 256, 256, 0, stream>>>(ei, rowptr, erank, ecol);

    // layer 0
    k_l0node<<<(NNODES + L0ROWS - 1) / L0ROWS, 256, 0, stream>>>(x, W0, attn0, ar, ac, h0b);
    k_l0edge<<<(NNODES + 3) / 4, 256, 0, stream>>>(rowptr, ecol, ar, ac, h0b, W1, h1);

    // layer 1
    k_fused1<<<(NNODES + 3) / 4, 256, 0, stream>>>(rowptr, ecol, h1, attn1, dout);
}

// Round 11
// 137.266 us; speedup vs baseline: 1.2399x; 1.1428x over previous
//
#include <hip/hip_runtime.h>
#include <math.h>

#define NNODES 50000
#define NEDGES 800000
#define SCAN_NB ((NNODES + 255) / 256)   // 196

typedef __attribute__((ext_vector_type(8))) short short8;
typedef __attribute__((ext_vector_type(4))) float f32x4;

// butterfly reductions: result valid in ALL lanes
__device__ inline float bsum64(float v) {
    #pragma unroll
    for (int off = 1; off < 64; off <<= 1) v += __shfl_xor(v, off, 64);
    return v;
}

// pack two f32 -> 2x bf16 (RNE) in one uint (low short = a, high short = b)
__device__ inline unsigned packbf2(float a, float b) {
    unsigned ua = __float_as_uint(a);
    unsigned ub = __float_as_uint(b);
    ua = (ua + 0x7fffu + ((ua >> 16) & 1u)) >> 16;
    ub = (ub + 0x7fffu + ((ub >> 16) & 1u)) >> 16;
    return ua | (ub << 16);
}
__device__ inline float bflo(unsigned u) { return __uint_as_float(u << 16); }
__device__ inline float bfhi(unsigned u) { return __uint_as_float(u & 0xffff0000u); }

// ---- zero the degree counters ----
__global__ void k_zero(int* __restrict__ deg) {
    int i = blockIdx.x * blockDim.x + threadIdx.x;
    if (i < NNODES) deg[i] = 0;
}

// ---- CSR build: histogram + per-edge local rank ----
__global__ __launch_bounds__(256) void k_hist(const int* __restrict__ ei,
                                              int* __restrict__ deg,
                                              int* __restrict__ erank) {
    int e = blockIdx.x * blockDim.x + threadIdx.x;
    if (e >= NEDGES) return;
    erank[e] = atomicAdd(&deg[ei[e]], 1);
}

// ---- scan pass 1 ----
__global__ __launch_bounds__(256) void k_scan1(const int* __restrict__ deg,
                                               int* __restrict__ rowptr,
                                               int* __restrict__ bsum) {
    __shared__ int sh[256];
    int t = threadIdx.x;
    int idx = blockIdx.x * 256 + t;
    int v = (idx < NNODES) ? deg[idx] : 0;
    sh[t] = v;
    __syncthreads();
    #pragma unroll
    for (int off = 1; off < 256; off <<= 1) {
        int u = (t >= off) ? sh[t - off] : 0;
        __syncthreads();
        sh[t] += u;
        __syncthreads();
    }
    if (idx < NNODES) rowptr[idx] = sh[t] - v;
    if (t == 255) bsum[blockIdx.x] = sh[255];
}

// ---- scan pass 2 ----
__global__ __launch_bounds__(256) void k_scan2(const int* __restrict__ bsum,
                                               int* __restrict__ boff) {
    __shared__ int sh[256];
    int t = threadIdx.x;
    int v = (t < SCAN_NB) ? bsum[t] : 0;
    sh[t] = v;
    __syncthreads();
    #pragma unroll
    for (int off = 1; off < 256; off <<= 1) {
        int u = (t >= off) ? sh[t - off] : 0;
        __syncthreads();
        sh[t] += u;
        __syncthreads();
    }
    if (t < SCAN_NB) boff[t] = sh[t] - v;
}

// ---- scan pass 3 ----
__global__ __launch_bounds__(256) void k_scan3(int* __restrict__ rowptr,
                                               const int* __restrict__ boff) {
    int idx = blockIdx.x * 256 + threadIdx.x;
    if (idx < NNODES) rowptr[idx] += boff[blockIdx.x];
    if (idx == 0) rowptr[NNODES] = NEDGES;
}

// ---- CSR build: simple scatter (no atomic; rank precomputed) ----
__global__ __launch_bounds__(256) void k_scatter(const int* __restrict__ ei,
                                                 const int* __restrict__ rowptr,
                                                 const int* __restrict__ erank,
                                                 int* __restrict__ ecol) {
    int e = blockIdx.x * blockDim.x + threadIdx.x;
    if (e >= NEDGES) return;
    int row = ei[e], col = ei[NEDGES + e];
    ecol[rowptr[row] + erank[e]] = col;
}

// ---- W prep: split W into bf16 hi/lo, pre-swizzled into MFMA B-fragment order ----
// B frag (16x16x32): lane holds B[k=(lane>>4)*8+i][col=lane&15]; streams indexed
// shorts[((kc*8+ct)*64+lane)*8+i]  (kc = k/32, ct = col/16)
__global__ __launch_bounds__(256) void k_wprep(const float* __restrict__ W,
                                               unsigned short* __restrict__ Whi,
                                               unsigned short* __restrict__ Wlo) {
    int tid = blockIdx.x * 256 + threadIdx.x;
    if (tid >= 128 * 128) return;
    int i = tid & 7, lane = (tid >> 3) & 63, ct = (tid >> 9) & 7, kc = tid >> 12;
    int k = kc * 32 + (lane >> 4) * 8 + i;
    int col = ct * 16 + (lane & 15);
    float v = W[k * 128 + col];
    unsigned hb = packbf2(v, 0.f) & 0xffffu;
    float hv = __uint_as_float(hb << 16);
    unsigned lb = packbf2(v - hv, 0.f) & 0xffffu;
    Whi[tid] = (unsigned short)hb;
    Wlo[tid] = (unsigned short)lb;
}

// ---- layer 0 node work: split-bf16 MFMA GEMM + attn dots + h0b pack, no LDS ----
// wave w handles rows n0 = blk*64 + w*16 .. +15.  A frag: row=lane&15, k=(lane>>4)*8+i.
// C/D: col = ct*16 + (lane&15), row = (lane>>4)*4 + reg   [m89-verified]
__global__ __launch_bounds__(256) void k_l0node(const float* __restrict__ x,
                                                const unsigned short* __restrict__ Whi,
                                                const unsigned short* __restrict__ Wlo,
                                                const float* __restrict__ attn0,
                                                float* __restrict__ ar,
                                                float* __restrict__ ac,
                                                unsigned* __restrict__ h0b) {
    int t = threadIdx.x;
    int w = t >> 6, lane = t & 63;
    int n0 = blockIdx.x * 64 + w * 16;
    int c16 = lane & 15, grp = lane >> 4;
    int arow = n0 + c16;                   // this lane's A-fragment row
    bool rowok = arow < NNODES;

    f32x4 acc[8];
    #pragma unroll
    for (int ct = 0; ct < 8; ct++) acc[ct] = (f32x4){0.f, 0.f, 0.f, 0.f};

    const uint4* WH = (const uint4*)Whi;   // 8 shorts per uint4 = one lane-fragment
    const uint4* WL = (const uint4*)Wlo;

    for (int kc = 0; kc < 4; kc++) {
        // load + split this lane's 8 x-values
        float xv[8];
        if (rowok) {
            *(float4*)&xv[0] = *(const float4*)&x[arow * 128 + kc * 32 + grp * 8];
            *(float4*)&xv[4] = *(const float4*)&x[arow * 128 + kc * 32 + grp * 8 + 4];
        } else {
            #pragma unroll
            for (int i = 0; i < 8; i++) xv[i] = 0.f;
        }
        unsigned ah[4], al[4];
        #pragma unroll
        for (int i = 0; i < 4; i++) ah[i] = packbf2(xv[2 * i], xv[2 * i + 1]);
        #pragma unroll
        for (int i = 0; i < 4; i++) {
            float l0 = xv[2 * i] - bflo(ah[i]);
            float l1 = xv[2 * i + 1] - bfhi(ah[i]);
            al[i] = packbf2(l0, l1);
        }
        short8 a_h = *(short8*)ah;
        short8 a_l = *(short8*)al;

        #pragma unroll
        for (int ct = 0; ct < 8; ct++) {
            uint4 whv = WH[(kc * 8 + ct) * 64 + lane];
            uint4 wlv = WL[(kc * 8 + ct) * 64 + lane];
            short8 b_h = *(short8*)&whv;
            short8 b_l = *(short8*)&wlv;
            acc[ct] = __builtin_amdgcn_mfma_f32_16x16x32_bf16(a_h, b_h, acc[ct], 0, 0, 0);
            acc[ct] = __builtin_amdgcn_mfma_f32_16x16x32_bf16(a_h, b_l, acc[ct], 0, 0, 0);
            acc[ct] = __builtin_amdgcn_mfma_f32_16x16x32_bf16(a_l, b_h, acc[ct], 0, 0, 0);
        }
    }

    // attention dots straight from accumulators
    #pragma unroll
    for (int reg = 0; reg < 4; reg++) {
        float pr0 = 0.f, pc0 = 0.f, pr1 = 0.f, pc1 = 0.f;
        #pragma unroll
        for (int ct = 0; ct < 4; ct++) {
            float v = acc[ct][reg];
            int ch = ct * 16 + c16;
            pr0 += v * attn0[ch];
            pc0 += v * attn0[64 + ch];
        }
        #pragma unroll
        for (int ct = 4; ct < 8; ct++) {
            float v = acc[ct][reg];
            int ch = (ct - 4) * 16 + c16;
            pr1 += v * attn0[128 + ch];
            pc1 += v * attn0[192 + ch];
        }
        #pragma unroll
        for (int off = 1; off < 16; off <<= 1) {
            pr0 += __shfl_xor(pr0, off, 64);
            pc0 += __shfl_xor(pc0, off, 64);
            pr1 += __shfl_xor(pr1, off, 64);
            pc1 += __shfl_xor(pc1, off, 64);
        }
        int n = n0 + grp * 4 + reg;
        if (c16 == 0 && n < NNODES) {
            ar[n * 2] = pr0;     ac[n * 2] = pc0;
            ar[n * 2 + 1] = pr1; ac[n * 2 + 1] = pc1;
        }
    }

    // h0b pack: thread holds (ch, ch+64) as (acc[ct], acc[ct+4]) for same c16
    #pragma unroll
    for (int reg = 0; reg < 4; reg++) {
        int n = n0 + grp * 4 + reg;
        if (n < NNODES) {
            #pragma unroll
            for (int ct = 0; ct < 4; ct++)
                h0b[n * 64 + ct * 16 + c16] = packbf2(acc[ct][reg], acc[ct + 4][reg]);
        }
    }
}

// ---- layer 0 edge work: softmax weights (no max-subtract) + aggregation
//      + relu + W1 transform -> h1[N,2].  One wave per node. ----
__global__ __launch_bounds__(256) void k_l0edge(const int* __restrict__ rowptr,
                                                const int* __restrict__ ecol,
                                                const float* __restrict__ ar,
                                                const float* __restrict__ ac,
                                                const unsigned* __restrict__ h0b,
                                                const float* __restrict__ W1,
                                                float* __restrict__ h1) {
    int w = threadIdx.x >> 6, lane = threadIdx.x & 63;
    int n = blockIdx.x * 4 + w;
    if (n >= NNODES) return;
    int beg = rowptr[n];
    int deg = rowptr[n + 1] - beg;
    float arn0 = ar[n * 2], arn1 = ar[n * 2 + 1];
    int esub = lane >> 4;
    int c16 = lane & 15;
    float accA[4] = {0.f, 0.f, 0.f, 0.f};
    float accB[4] = {0.f, 0.f, 0.f, 0.f};
    float s0t = 0.f, s1t = 0.f;
    for (int wb = 0; wb < deg; wb += 64) {
        int cnt = deg - wb; if (cnt > 64) cnt = 64;
        float p0 = 0.f, p1 = 0.f; int colr = 0;
        if (lane < cnt) {
            colr = ecol[beg + wb + lane];
            float2 acv = ((const float2*)ac)[colr];
            float a0 = arn0 + acv.x, a1 = arn1 + acv.y;
            a0 = a0 > 0.f ? a0 : 0.2f * a0;
            a1 = a1 > 0.f ? a1 : 0.2f * a1;
            p0 = __expf(a0); p1 = __expf(a1);
            s0t += p0; s1t += p1;
        }
        int tmax = (cnt + 3) >> 2;
        for (int tt = 0; tt < tmax; tt++) {
            int i4 = tt * 4 + esub;
            int colx = __shfl(colr, i4, 64);
            float q0 = __shfl(p0, i4, 64);
            float q1 = __shfl(p1, i4, 64);
            if (i4 < cnt) {
                const uint4 u = *(const uint4*)(h0b + colx * 64 + c16 * 4);
                accA[0] += q0 * bflo(u.x); accB[0] += q1 * bfhi(u.x);
                accA[1] += q0 * bflo(u.y); accB[1] += q1 * bfhi(u.y);
                accA[2] += q0 * bflo(u.z); accB[2] += q1 * bfhi(u.z);
                accA[3] += q0 * bflo(u.w); accB[3] += q1 * bfhi(u.w);
            }
        }
    }
    float s0 = bsum64(s0t), s1 = bsum64(s1t);
    #pragma unroll
    for (int jj = 0; jj < 4; jj++) {
        accA[jj] += __shfl_xor(accA[jj], 16, 64);
        accA[jj] += __shfl_xor(accA[jj], 32, 64);
        accB[jj] += __shfl_xor(accB[jj], 16, 64);
        accB[jj] += __shfl_xor(accB[jj], 32, 64);
    }
    float si0 = deg ? 0.5f / s0 : 0.f;
    float si1 = deg ? 0.5f / s1 : 0.f;
    float pA = 0.f, pB = 0.f;
    #pragma unroll
    for (int jj = 0; jj < 4; jj++) {
        float o = si0 * accA[jj] + si1 * accB[jj];
        o = o > 0.f ? o : 0.f;   // relu
        float2 wv = ((const float2*)W1)[c16 * 4 + jj];
        pA += o * wv.x; pB += o * wv.y;
    }
    #pragma unroll
    for (int off = 1; off < 16; off <<= 1) {
        pA += __shfl_xor(pA, off, 64);
        pB += __shfl_xor(pB, off, 64);
    }
    if (lane == 0) { h1[n * 2] = pA; h1[n * 2 + 1] = pB; }
}

// ---- layer 1 fused: wave per node, lane = edge, plain (no-max) softmax ----
__global__ __launch_bounds__(256) void k_fused1(const int* __restrict__ rowptr,
                                                const int* __restrict__ ecol,
                                                const float* __restrict__ h1,
                                                const float* __restrict__ attn1,
                                                float* __restrict__ dout) {
    int w = threadIdx.x >> 6, lane = threadIdx.x & 63;
    int n = blockIdx.x * 4 + w;
    if (n >= NNODES) return;
    int beg = rowptr[n], end = rowptr[n + 1];
    if (beg == end) { if (lane == 0) dout[n] = 0.f; return; }
    float w01 = attn1[1], w11 = attn1[3];
    float base0 = attn1[0] * h1[n * 2];
    float base1 = attn1[2] * h1[n * 2 + 1];
    float s0 = 0.f, s1 = 0.f, acc0 = 0.f, acc1 = 0.f;
    for (int i = beg + lane; i < end; i += 64) {
        int col = ecol[i];
        float2 v = ((const float2*)h1)[col];
        float a0 = base0 + w01 * v.x;
        float a1 = base1 + w11 * v.y;
        a0 = a0 > 0.f ? a0 : 0.2f * a0;
        a1 = a1 > 0.f ? a1 : 0.2f * a1;
        float p0 = __expf(a0), p1 = __expf(a1);
        s0 += p0; acc0 += p0 * v.x;
        s1 += p1; acc1 += p1 * v.y;
    }
    s0 = bsum64(s0); s1 = bsum64(s1);
    acc0 = bsum64(acc0); acc1 = bsum64(acc1);
    if (lane == 0) dout[n] = 0.5f * (acc0 / s0 + acc1 / s1);
}

extern "C" void kernel_launch(void* const* d_in, const int* in_sizes, int n_in,
                              void* d_out, int out_size, void* d_ws, size_t ws_size,
                              hipStream_t stream) {
    const float* x     = (const float*)d_in[0];
    const int*   ei    = (const int*)d_in[1];
    const float* W0    = (const float*)d_in[2];
    const float* attn0 = (const float*)d_in[3];
    const float* W1    = (const float*)d_in[4];
    const float* attn1 = (const float*)d_in[5];
    float* dout = (float*)d_out;

    float* ws = (float*)d_ws;
    float*          ar     = ws;                             // N*2
    float*          ac     = ar + NNODES * 2;                // N*2
    float*          h1     = ac + NNODES * 2;                // N*2
    unsigned*       h0b    = (unsigned*)(h1 + NNODES * 2);   // N*64
    unsigned short* Whi    = (unsigned short*)(h0b + NNODES * 64); // 128*128 ushort
    unsigned short* Wlo    = Whi + 128 * 128;                // 128*128 ushort
    int*            deg    = (int*)(Wlo + 128 * 128);        // N
    int*            rowptr = deg + NNODES;                   // N+1
    int*            erank  = rowptr + NNODES + 1;            // E
    int*            bsum   = erank + NEDGES;                 // SCAN_NB
    int*            boff   = bsum + SCAN_NB;                 // SCAN_NB
    int*            ecol   = boff + SCAN_NB;                 // E

    // CSR build
    k_zero<<<(NNODES + 255) / 256, 256, 0, stream>>>(deg);
    k_hist<<<(NEDGES + 255) / 256, 256, 0, stream>>>(ei, deg, erank);
    k_scan1<<<SCAN_NB, 256, 0, stream>>>(deg, rowptr, bsum);
    k_scan2<<<1, 256, 0, stream>>>(bsum, boff);
    k_scan3<<<SCAN_NB, 256, 0, stream>>>(rowptr, boff);
    k_scatter<<<(NEDGES + 255) / 256, 256, 0, stream>>>(ei, rowptr, erank, ecol);

    // layer 0
    k_wprep<<<(128 * 128 + 255) / 256, 256, 0, stream>>>(W0, Whi, Wlo);
    k_l0node<<<(NNODES + 63) / 64, 256, 0, stream>>>(x, Whi, Wlo, attn0, ar, ac, h0b);
    k_l0edge<<<(NNODES + 3) / 4, 256, 0, stream>>>(rowptr, ecol, ar, ac, h0b, W1, h1);

    // layer 1
    k_fused1<<<(NNODES + 3) / 4, 256, 0, stream>>>(rowptr, ecol, h1, attn1, dout);
}

// Round 12
// 107.846 us; speedup vs baseline: 1.5782x; 1.2728x over previous
//
#include <hip/hip_runtime.h>
#include <math.h>

#define NNODES 50000
#define NEDGES 800000
#define NBKT 196          // buckets of 256 rows (196*256 = 50176 >= N)
#define BKT_CAP 5120      // mean 4096, sigma ~64 -> +16 sigma headroom
#define EPB 2048          // edges per kA block

typedef __attribute__((ext_vector_type(8))) short short8;
typedef __attribute__((ext_vector_type(4))) float f32x4;

// butterfly reductions: result valid in ALL lanes
__device__ inline float bsum64(float v) {
    #pragma unroll
    for (int off = 1; off < 64; off <<= 1) v += __shfl_xor(v, off, 64);
    return v;
}

// pack two f32 -> 2x bf16 (RNE) in one uint (low short = a, high short = b)
__device__ inline unsigned packbf2(float a, float b) {
    unsigned ua = __float_as_uint(a);
    unsigned ub = __float_as_uint(b);
    ua = (ua + 0x7fffu + ((ua >> 16) & 1u)) >> 16;
    ub = (ub + 0x7fffu + ((ub >> 16) & 1u)) >> 16;
    return ua | (ub << 16);
}
__device__ inline float bflo(unsigned u) { return __uint_as_float(u << 16); }
__device__ inline float bfhi(unsigned u) { return __uint_as_float(u & 0xffff0000u); }

// ---- zero the bucket cursors ----
__global__ void k_z0(int* __restrict__ gcur) {
    int i = threadIdx.x;
    if (i < NBKT) gcur[i] = 0;
}

// ---- CSR pass A: bin edges into 196 bucket staging regions ----
// entry = (rowlocal<<16) | col   (rowlocal<256, col<65536)
__global__ __launch_bounds__(256) void k_binA(const int* __restrict__ ei,
                                              int* __restrict__ gcur,
                                              unsigned* __restrict__ stag) {
    __shared__ int lh[NBKT];      // histogram, then local cursor
    __shared__ int lbase[NBKT];
    int t = threadIdx.x;
    for (int i = t; i < NBKT; i += 256) lh[i] = 0;
    __syncthreads();
    int e0 = blockIdx.x * EPB;
    int rows[8], cols[8];
    #pragma unroll
    for (int i = 0; i < 8; i++) {
        int e = e0 + i * 256 + t;
        if (e < NEDGES) {
            rows[i] = ei[e];
            cols[i] = ei[NEDGES + e];
            atomicAdd(&lh[rows[i] >> 8], 1);
        }
    }
    __syncthreads();
    for (int i = t; i < NBKT; i += 256) {
        lbase[i] = atomicAdd(&gcur[i], lh[i]);
        lh[i] = 0;
    }
    __syncthreads();
    #pragma unroll
    for (int i = 0; i < 8; i++) {
        int e = e0 + i * 256 + t;
        if (e < NEDGES) {
            int b = rows[i] >> 8;
            int rank = atomicAdd(&lh[b], 1);
            stag[b * BKT_CAP + lbase[b] + rank] =
                ((unsigned)(rows[i] & 255) << 16) | (unsigned)cols[i];
        }
    }
}

// ---- CSR pass B: exclusive scan of bucket counts -> bucket bases ----
__global__ __launch_bounds__(256) void k_binB(const int* __restrict__ gcur,
                                              int* __restrict__ bbase) {
    __shared__ int sh[256];
    int t = threadIdx.x;
    int v = (t < NBKT) ? gcur[t] : 0;
    sh[t] = v;
    __syncthreads();
    #pragma unroll
    for (int off = 1; off < 256; off <<= 1) {
        int u = (t >= off) ? sh[t - off] : 0;
        __syncthreads();
        sh[t] += u;
        __syncthreads();
    }
    if (t < NBKT) bbase[t] = sh[t] - v;
}

// ---- CSR pass C: per bucket -> rowptr + row-grouped ecol (LDS staging) ----
__global__ __launch_bounds__(256) void k_binC(const int* __restrict__ gcur,
                                              const int* __restrict__ bbase,
                                              const unsigned* __restrict__ stag,
                                              int* __restrict__ rowptr,
                                              int* __restrict__ ecol) {
    __shared__ int dg[256];
    __shared__ int sc[256];
    __shared__ int cur[256];
    __shared__ int lout[BKT_CAP];   // 20 KB
    int b = blockIdx.x, t = threadIdx.x;
    int cnt = gcur[b];
    int base = bbase[b];
    dg[t] = 0;
    __syncthreads();
    for (int i = t; i < cnt; i += 256)
        atomicAdd(&dg[stag[b * BKT_CAP + i] >> 16], 1);
    __syncthreads();
    int v = dg[t];
    sc[t] = v;
    __syncthreads();
    #pragma unroll
    for (int off = 1; off < 256; off <<= 1) {
        int u = (t >= off) ? sc[t - off] : 0;
        __syncthreads();
        sc[t] += u;
        __syncthreads();
    }
    int excl = sc[t] - v;
    int gidx = b * 256 + t;
    if (gidx <= NNODES) rowptr[gidx] = base + excl;   // bucket 195 t=80 writes sentinel = E
    cur[t] = excl;
    __syncthreads();
    for (int i = t; i < cnt; i += 256) {
        unsigned p = stag[b * BKT_CAP + i];
        int pos = atomicAdd(&cur[p >> 16], 1);
        lout[pos] = (int)(p & 0xffffu);
    }
    __syncthreads();
    for (int i = t; i < cnt; i += 256) ecol[base + i] = lout[i];
}

// ---- W prep: split W into bf16 hi/lo, pre-swizzled into MFMA B-fragment order ----
__global__ __launch_bounds__(256) void k_wprep(const float* __restrict__ W,
                                               unsigned short* __restrict__ Whi,
                                               unsigned short* __restrict__ Wlo) {
    int tid = blockIdx.x * 256 + threadIdx.x;
    if (tid >= 128 * 128) return;
    int i = tid & 7, lane = (tid >> 3) & 63, ct = (tid >> 9) & 7, kc = tid >> 12;
    int k = kc * 32 + (lane >> 4) * 8 + i;
    int col = ct * 16 + (lane & 15);
    float v = W[k * 128 + col];
    unsigned hb = packbf2(v, 0.f) & 0xffffu;
    float hv = __uint_as_float(hb << 16);
    unsigned lb = packbf2(v - hv, 0.f) & 0xffffu;
    Whi[tid] = (unsigned short)hb;
    Wlo[tid] = (unsigned short)lb;
}

// ---- layer 0 node work: split-bf16 MFMA GEMM + attn dots + h0b pack, no LDS ----
__global__ __launch_bounds__(256) void k_l0node(const float* __restrict__ x,
                                                const unsigned short* __restrict__ Whi,
                                                const unsigned short* __restrict__ Wlo,
                                                const float* __restrict__ attn0,
                                                float* __restrict__ ar,
                                                float* __restrict__ ac,
                                                unsigned* __restrict__ h0b) {
    int t = threadIdx.x;
    int w = t >> 6, lane = t & 63;
    int n0 = blockIdx.x * 64 + w * 16;
    int c16 = lane & 15, grp = lane >> 4;
    int arow = n0 + c16;
    bool rowok = arow < NNODES;

    f32x4 acc[8];
    #pragma unroll
    for (int ct = 0; ct < 8; ct++) acc[ct] = (f32x4){0.f, 0.f, 0.f, 0.f};

    const uint4* WH = (const uint4*)Whi;
    const uint4* WL = (const uint4*)Wlo;

    for (int kc = 0; kc < 4; kc++) {
        float xv[8];
        if (rowok) {
            *(float4*)&xv[0] = *(const float4*)&x[arow * 128 + kc * 32 + grp * 8];
            *(float4*)&xv[4] = *(const float4*)&x[arow * 128 + kc * 32 + grp * 8 + 4];
        } else {
            #pragma unroll
            for (int i = 0; i < 8; i++) xv[i] = 0.f;
        }
        unsigned ah[4], al[4];
        #pragma unroll
        for (int i = 0; i < 4; i++) ah[i] = packbf2(xv[2 * i], xv[2 * i + 1]);
        #pragma unroll
        for (int i = 0; i < 4; i++) {
            float l0 = xv[2 * i] - bflo(ah[i]);
            float l1 = xv[2 * i + 1] - bfhi(ah[i]);
            al[i] = packbf2(l0, l1);
        }
        short8 a_h = *(short8*)ah;
        short8 a_l = *(short8*)al;

        #pragma unroll
        for (int ct = 0; ct < 8; ct++) {
            uint4 whv = WH[(kc * 8 + ct) * 64 + lane];
            uint4 wlv = WL[(kc * 8 + ct) * 64 + lane];
            short8 b_h = *(short8*)&whv;
            short8 b_l = *(short8*)&wlv;
            acc[ct] = __builtin_amdgcn_mfma_f32_16x16x32_bf16(a_h, b_h, acc[ct], 0, 0, 0);
            acc[ct] = __builtin_amdgcn_mfma_f32_16x16x32_bf16(a_h, b_l, acc[ct], 0, 0, 0);
            acc[ct] = __builtin_amdgcn_mfma_f32_16x16x32_bf16(a_l, b_h, acc[ct], 0, 0, 0);
        }
    }

    #pragma unroll
    for (int reg = 0; reg < 4; reg++) {
        float pr0 = 0.f, pc0 = 0.f, pr1 = 0.f, pc1 = 0.f;
        #pragma unroll
        for (int ct = 0; ct < 4; ct++) {
            float v = acc[ct][reg];
            int ch = ct * 16 + c16;
            pr0 += v * attn0[ch];
            pc0 += v * attn0[64 + ch];
        }
        #pragma unroll
        for (int ct = 4; ct < 8; ct++) {
            float v = acc[ct][reg];
            int ch = (ct - 4) * 16 + c16;
            pr1 += v * attn0[128 + ch];
            pc1 += v * attn0[192 + ch];
        }
        #pragma unroll
        for (int off = 1; off < 16; off <<= 1) {
            pr0 += __shfl_xor(pr0, off, 64);
            pc0 += __shfl_xor(pc0, off, 64);
            pr1 += __shfl_xor(pr1, off, 64);
            pc1 += __shfl_xor(pc1, off, 64);
        }
        int n = n0 + grp * 4 + reg;
        if (c16 == 0 && n < NNODES) {
            ar[n * 2] = pr0;     ac[n * 2] = pc0;
            ar[n * 2 + 1] = pr1; ac[n * 2 + 1] = pc1;
        }
    }

    #pragma unroll
    for (int reg = 0; reg < 4; reg++) {
        int n = n0 + grp * 4 + reg;
        if (n < NNODES) {
            #pragma unroll
            for (int ct = 0; ct < 4; ct++)
                h0b[n * 64 + ct * 16 + c16] = packbf2(acc[ct][reg], acc[ct + 4][reg]);
        }
    }
}

// ---- layer 0 edge work: softmax weights (no max-subtract) + aggregation
//      + relu + W1 transform -> h1[N,2].  One wave per node. ----
__global__ __launch_bounds__(256) void k_l0edge(const int* __restrict__ rowptr,
                                                const int* __restrict__ ecol,
                                                const float* __restrict__ ar,
                                                const float* __restrict__ ac,
                                                const unsigned* __restrict__ h0b,
                                                const float* __restrict__ W1,
                                                float* __restrict__ h1) {
    int w = threadIdx.x >> 6, lane = threadIdx.x & 63;
    int n = blockIdx.x * 4 + w;
    if (n >= NNODES) return;
    int beg = rowptr[n];
    int deg = rowptr[n + 1] - beg;
    float arn0 = ar[n * 2], arn1 = ar[n * 2 + 1];
    int esub = lane >> 4;
    int c16 = lane & 15;
    float accA[4] = {0.f, 0.f, 0.f, 0.f};
    float accB[4] = {0.f, 0.f, 0.f, 0.f};
    float s0t = 0.f, s1t = 0.f;
    for (int wb = 0; wb < deg; wb += 64) {
        int cnt = deg - wb; if (cnt > 64) cnt = 64;
        float p0 = 0.f, p1 = 0.f; int colr = 0;
        if (lane < cnt) {
            colr = ecol[beg + wb + lane];
            float2 acv = ((const float2*)ac)[colr];
            float a0 = arn0 + acv.x, a1 = arn1 + acv.y;
            a0 = a0 > 0.f ? a0 : 0.2f * a0;
            a1 = a1 > 0.f ? a1 : 0.2f * a1;
            p0 = __expf(a0); p1 = __expf(a1);
            s0t += p0; s1t += p1;
        }
        int tmax = (cnt + 3) >> 2;
        for (int tt = 0; tt < tmax; tt++) {
            int i4 = tt * 4 + esub;
            int colx = __shfl(colr, i4, 64);
            float q0 = __shfl(p0, i4, 64);
            float q1 = __shfl(p1, i4, 64);
            if (i4 < cnt) {
                const uint4 u = *(const uint4*)(h0b + colx * 64 + c16 * 4);
                accA[0] += q0 * bflo(u.x); accB[0] += q1 * bfhi(u.x);
                accA[1] += q0 * bflo(u.y); accB[1] += q1 * bfhi(u.y);
                accA[2] += q0 * bflo(u.z); accB[2] += q1 * bfhi(u.z);
                accA[3] += q0 * bflo(u.w); accB[3] += q1 * bfhi(u.w);
            }
        }
    }
    float s0 = bsum64(s0t), s1 = bsum64(s1t);
    #pragma unroll
    for (int jj = 0; jj < 4; jj++) {
        accA[jj] += __shfl_xor(accA[jj], 16, 64);
        accA[jj] += __shfl_xor(accA[jj], 32, 64);
        accB[jj] += __shfl_xor(accB[jj], 16, 64);
        accB[jj] += __shfl_xor(accB[jj], 32, 64);
    }
    float si0 = deg ? 0.5f / s0 : 0.f;
    float si1 = deg ? 0.5f / s1 : 0.f;
    float pA = 0.f, pB = 0.f;
    #pragma unroll
    for (int jj = 0; jj < 4; jj++) {
        float o = si0 * accA[jj] + si1 * accB[jj];
        o = o > 0.f ? o : 0.f;   // relu
        float2 wv = ((const float2*)W1)[c16 * 4 + jj];
        pA += o * wv.x; pB += o * wv.y;
    }
    #pragma unroll
    for (int off = 1; off < 16; off <<= 1) {
        pA += __shfl_xor(pA, off, 64);
        pB += __shfl_xor(pB, off, 64);
    }
    if (lane == 0) { h1[n * 2] = pA; h1[n * 2 + 1] = pB; }
}

// ---- layer 1 fused: wave per node, lane = edge, plain (no-max) softmax ----
__global__ __launch_bounds__(256) void k_fused1(const int* __restrict__ rowptr,
                                                const int* __restrict__ ecol,
                                                const float* __restrict__ h1,
                                                const float* __restrict__ attn1,
                                                float* __restrict__ dout) {
    int w = threadIdx.x >> 6, lane = threadIdx.x & 63;
    int n = blockIdx.x * 4 + w;
    if (n >= NNODES) return;
    int beg = rowptr[n], end = rowptr[n + 1];
    if (beg == end) { if (lane == 0) dout[n] = 0.f; return; }
    float w01 = attn1[1], w11 = attn1[3];
    float base0 = attn1[0] * h1[n * 2];
    float base1 = attn1[2] * h1[n * 2 + 1];
    float s0 = 0.f, s1 = 0.f, acc0 = 0.f, acc1 = 0.f;
    for (int i = beg + lane; i < end; i += 64) {
        int col = ecol[i];
        float2 v = ((const float2*)h1)[col];
        float a0 = base0 + w01 * v.x;
        float a1 = base1 + w11 * v.y;
        a0 = a0 > 0.f ? a0 : 0.2f * a0;
        a1 = a1 > 0.f ? a1 : 0.2f * a1;
        float p0 = __expf(a0), p1 = __expf(a1);
        s0 += p0; acc0 += p0 * v.x;
        s1 += p1; acc1 += p1 * v.y;
    }
    s0 = bsum64(s0); s1 = bsum64(s1);
    acc0 = bsum64(acc0); acc1 = bsum64(acc1);
    if (lane == 0) dout[n] = 0.5f * (acc0 / s0 + acc1 / s1);
}

extern "C" void kernel_launch(void* const* d_in, const int* in_sizes, int n_in,
                              void* d_out, int out_size, void* d_ws, size_t ws_size,
                              hipStream_t stream) {
    const float* x     = (const float*)d_in[0];
    const int*   ei    = (const int*)d_in[1];
    const float* W0    = (const float*)d_in[2];
    const float* attn0 = (const float*)d_in[3];
    const float* W1    = (const float*)d_in[4];
    const float* attn1 = (const float*)d_in[5];
    float* dout = (float*)d_out;

    float* ws = (float*)d_ws;
    float*          ar     = ws;                             // N*2
    float*          ac     = ar + NNODES * 2;                // N*2
    float*          h1     = ac + NNODES * 2;                // N*2
    unsigned*       h0b    = (unsigned*)(h1 + NNODES * 2);   // N*64
    unsigned short* Whi    = (unsigned short*)(h0b + NNODES * 64); // 128*128
    unsigned short* Wlo    = Whi + 128 * 128;                // 128*128
    int*            gcur   = (int*)(Wlo + 128 * 128);        // NBKT
    int*            bbase  = gcur + NBKT;                    // NBKT
    int*            rowptr = bbase + NBKT;                   // N+1
    unsigned*       stag   = (unsigned*)(rowptr + NNODES + 1); // NBKT*BKT_CAP
    int*            ecol   = (int*)(stag + NBKT * BKT_CAP);  // E

    // CSR build (bucketed, LDS-local scatter)
    k_z0<<<1, 256, 0, stream>>>(gcur);
    k_binA<<<(NEDGES + EPB - 1) / EPB, 256, 0, stream>>>(ei, gcur, stag);
    k_binB<<<1, 256, 0, stream>>>(gcur, bbase);
    k_binC<<<NBKT, 256, 0, stream>>>(gcur, bbase, stag, rowptr, ecol);

    // layer 0
    k_wprep<<<(128 * 128 + 255) / 256, 256, 0, stream>>>(W0, Whi, Wlo);
    k_l0node<<<(NNODES + 63) / 64, 256, 0, stream>>>(x, Whi, Wlo, attn0, ar, ac, h0b);
    k_l0edge<<<(NNODES + 3) / 4, 256, 0, stream>>>(rowptr, ecol, ar, ac, h0b, W1, h1);

    // layer 1
    k_fused1<<<(NNODES + 3) / 4, 256, 0, stream>>>(rowptr, ecol, h1, attn1, dout);
}

// Round 13
// 98.247 us; speedup vs baseline: 1.7323x; 1.0977x over previous
//
#include <hip/hip_runtime.h>
#include <math.h>

#define NNODES 50000
#define NEDGES 800000
#define NBKT 196          // buckets of 256 rows (196*256 = 50176 >= N)
#define BKT_CAP 5120      // mean 4096, sigma ~64 -> +16 sigma headroom
#define EPB 2048          // edges per binA block
#define NBA ((NEDGES + EPB - 1) / EPB)   // 391 binA blocks
#define NBN ((NNODES + 63) / 64)         // 782 l0node blocks

typedef __attribute__((ext_vector_type(8))) short short8;
typedef __attribute__((ext_vector_type(4))) float f32x4;

__device__ inline float bsum64(float v) {
    #pragma unroll
    for (int off = 1; off < 64; off <<= 1) v += __shfl_xor(v, off, 64);
    return v;
}

// pack two f32 -> 2x bf16 (RNE) in one uint (low short = a, high short = b)
__device__ inline unsigned packbf2(float a, float b) {
    unsigned ua = __float_as_uint(a);
    unsigned ub = __float_as_uint(b);
    ua = (ua + 0x7fffu + ((ua >> 16) & 1u)) >> 16;
    ub = (ub + 0x7fffu + ((ub >> 16) & 1u)) >> 16;
    return ua | (ub << 16);
}
__device__ inline float bflo(unsigned u) { return __uint_as_float(u << 16); }
__device__ inline float bfhi(unsigned u) { return __uint_as_float(u & 0xffff0000u); }

// ==== K1: W split/swizzle prep + zero bucket cursors ====
__global__ __launch_bounds__(256) void k_prep(const float* __restrict__ W,
                                              unsigned short* __restrict__ Whi,
                                              unsigned short* __restrict__ Wlo,
                                              int* __restrict__ gcur) {
    if (blockIdx.x == 64) {
        int i = threadIdx.x;
        if (i < NBKT) gcur[i] = 0;
        return;
    }
    int tid = blockIdx.x * 256 + threadIdx.x;
    int i = tid & 7, lane = (tid >> 3) & 63, ct = (tid >> 9) & 7, kc = tid >> 12;
    int k = kc * 32 + (lane >> 4) * 8 + i;
    int col = ct * 16 + (lane & 15);
    float v = W[k * 128 + col];
    unsigned hb = packbf2(v, 0.f) & 0xffffu;
    float hv = __uint_as_float(hb << 16);
    unsigned lb = packbf2(v - hv, 0.f) & 0xffffu;
    Whi[tid] = (unsigned short)hb;
    Wlo[tid] = (unsigned short)lb;
}

// ==== K2: fat kernel = binA (blocks 0..NBA-1)  ||  l0node (blocks NBA..) ====
__global__ __launch_bounds__(256) void k_nodeA(const int* __restrict__ ei,
                                               int* __restrict__ gcur,
                                               unsigned* __restrict__ stag,
                                               const float* __restrict__ x,
                                               const unsigned short* __restrict__ Whi,
                                               const unsigned short* __restrict__ Wlo,
                                               const float* __restrict__ attn0,
                                               float* __restrict__ ar,
                                               float* __restrict__ ac,
                                               unsigned* __restrict__ h0b) {
    __shared__ int lh[NBKT];
    __shared__ int lbase[NBKT];
    int t = threadIdx.x;

    if (blockIdx.x < NBA) {
        // ---- binA: bin edges into bucket staging; entry=(rowlocal<<16)|col ----
        for (int i = t; i < NBKT; i += 256) lh[i] = 0;
        __syncthreads();
        int e0 = blockIdx.x * EPB;
        int rows[8], cols[8];
        #pragma unroll
        for (int i = 0; i < 8; i++) {
            int e = e0 + i * 256 + t;
            if (e < NEDGES) {
                rows[i] = ei[e];
                cols[i] = ei[NEDGES + e];
                atomicAdd(&lh[rows[i] >> 8], 1);
            }
        }
        __syncthreads();
        for (int i = t; i < NBKT; i += 256) {
            lbase[i] = atomicAdd(&gcur[i], lh[i]);
            lh[i] = 0;
        }
        __syncthreads();
        #pragma unroll
        for (int i = 0; i < 8; i++) {
            int e = e0 + i * 256 + t;
            if (e < NEDGES) {
                int b = rows[i] >> 8;
                int rank = atomicAdd(&lh[b], 1);
                stag[b * BKT_CAP + lbase[b] + rank] =
                    ((unsigned)(rows[i] & 255) << 16) | (unsigned)cols[i];
            }
        }
        return;
    }

    // ---- l0node: split-bf16 MFMA GEMM + attn dots + h0b pack ----
    int bid = blockIdx.x - NBA;
    int w = t >> 6, lane = t & 63;
    int n0 = bid * 64 + w * 16;
    int c16 = lane & 15, grp = lane >> 4;
    int arow = n0 + c16;
    bool rowok = arow < NNODES;

    f32x4 acc[8];
    #pragma unroll
    for (int ct = 0; ct < 8; ct++) acc[ct] = (f32x4){0.f, 0.f, 0.f, 0.f};

    const uint4* WH = (const uint4*)Whi;
    const uint4* WL = (const uint4*)Wlo;

    for (int kc = 0; kc < 4; kc++) {
        float xv[8];
        if (rowok) {
            *(float4*)&xv[0] = *(const float4*)&x[arow * 128 + kc * 32 + grp * 8];
            *(float4*)&xv[4] = *(const float4*)&x[arow * 128 + kc * 32 + grp * 8 + 4];
        } else {
            #pragma unroll
            for (int i = 0; i < 8; i++) xv[i] = 0.f;
        }
        unsigned ah[4], al[4];
        #pragma unroll
        for (int i = 0; i < 4; i++) ah[i] = packbf2(xv[2 * i], xv[2 * i + 1]);
        #pragma unroll
        for (int i = 0; i < 4; i++) {
            float l0 = xv[2 * i] - bflo(ah[i]);
            float l1 = xv[2 * i + 1] - bfhi(ah[i]);
            al[i] = packbf2(l0, l1);
        }
        short8 a_h = *(short8*)ah;
        short8 a_l = *(short8*)al;

        #pragma unroll
        for (int ct = 0; ct < 8; ct++) {
            uint4 whv = WH[(kc * 8 + ct) * 64 + lane];
            uint4 wlv = WL[(kc * 8 + ct) * 64 + lane];
            short8 b_h = *(short8*)&whv;
            short8 b_l = *(short8*)&wlv;
            acc[ct] = __builtin_amdgcn_mfma_f32_16x16x32_bf16(a_h, b_h, acc[ct], 0, 0, 0);
            acc[ct] = __builtin_amdgcn_mfma_f32_16x16x32_bf16(a_h, b_l, acc[ct], 0, 0, 0);
            acc[ct] = __builtin_amdgcn_mfma_f32_16x16x32_bf16(a_l, b_h, acc[ct], 0, 0, 0);
        }
    }

    #pragma unroll
    for (int reg = 0; reg < 4; reg++) {
        float pr0 = 0.f, pc0 = 0.f, pr1 = 0.f, pc1 = 0.f;
        #pragma unroll
        for (int ct = 0; ct < 4; ct++) {
            float v = acc[ct][reg];
            int ch = ct * 16 + c16;
            pr0 += v * attn0[ch];
            pc0 += v * attn0[64 + ch];
        }
        #pragma unroll
        for (int ct = 4; ct < 8; ct++) {
            float v = acc[ct][reg];
            int ch = (ct - 4) * 16 + c16;
            pr1 += v * attn0[128 + ch];
            pc1 += v * attn0[192 + ch];
        }
        #pragma unroll
        for (int off = 1; off < 16; off <<= 1) {
            pr0 += __shfl_xor(pr0, off, 64);
            pc0 += __shfl_xor(pc0, off, 64);
            pr1 += __shfl_xor(pr1, off, 64);
            pc1 += __shfl_xor(pc1, off, 64);
        }
        int n = n0 + grp * 4 + reg;
        if (c16 == 0 && n < NNODES) {
            ar[n * 2] = pr0;     ac[n * 2] = pc0;
            ar[n * 2 + 1] = pr1; ac[n * 2 + 1] = pc1;
        }
    }

    #pragma unroll
    for (int reg = 0; reg < 4; reg++) {
        int n = n0 + grp * 4 + reg;
        if (n < NNODES) {
            #pragma unroll
            for (int ct = 0; ct < 4; ct++)
                h0b[n * 64 + ct * 16 + c16] = packbf2(acc[ct][reg], acc[ct + 4][reg]);
        }
    }
}

// ==== K3: per-bucket -> rowptr + row-grouped ecol (inline bucket-base scan) ====
__global__ __launch_bounds__(256) void k_binC(const int* __restrict__ gcur,
                                              const unsigned* __restrict__ stag,
                                              int* __restrict__ rowptr,
                                              int* __restrict__ ecol) {
    __shared__ int sh[256];
    __shared__ int dg[256];
    __shared__ int sc[256];
    __shared__ int cur[256];
    __shared__ int lout[BKT_CAP];   // 20 KB
    int b = blockIdx.x, t = threadIdx.x;
    // inline exclusive scan of all bucket counts (196 ints, redundant per block)
    int gv = (t < NBKT) ? gcur[t] : 0;
    sh[t] = gv;
    __syncthreads();
    #pragma unroll
    for (int off = 1; off < 256; off <<= 1) {
        int u = (t >= off) ? sh[t - off] : 0;
        __syncthreads();
        sh[t] += u;
        __syncthreads();
    }
    int cnt = gcur[b];
    int base = sh[b] - cnt;         // exclusive prefix for this bucket
    dg[t] = 0;
    __syncthreads();
    for (int i = t; i < cnt; i += 256)
        atomicAdd(&dg[stag[b * BKT_CAP + i] >> 16], 1);
    __syncthreads();
    int v = dg[t];
    sc[t] = v;
    __syncthreads();
    #pragma unroll
    for (int off = 1; off < 256; off <<= 1) {
        int u = (t >= off) ? sc[t - off] : 0;
        __syncthreads();
        sc[t] += u;
        __syncthreads();
    }
    int excl = sc[t] - v;
    int gidx = b * 256 + t;
    if (gidx <= NNODES) rowptr[gidx] = base + excl;
    cur[t] = excl;
    __syncthreads();
    for (int i = t; i < cnt; i += 256) {
        unsigned p = stag[b * BKT_CAP + i];
        int pos = atomicAdd(&cur[p >> 16], 1);
        lout[pos] = (int)(p & 0xffffu);
    }
    __syncthreads();
    for (int i = t; i < cnt; i += 256) ecol[base + i] = lout[i];
}

// ==== K4: layer 0 edge work ====
__global__ __launch_bounds__(256) void k_l0edge(const int* __restrict__ rowptr,
                                                const int* __restrict__ ecol,
                                                const float* __restrict__ ar,
                                                const float* __restrict__ ac,
                                                const unsigned* __restrict__ h0b,
                                                const float* __restrict__ W1,
                                                float* __restrict__ h1) {
    int w = threadIdx.x >> 6, lane = threadIdx.x & 63;
    int n = blockIdx.x * 4 + w;
    if (n >= NNODES) return;
    int beg = rowptr[n];
    int deg = rowptr[n + 1] - beg;
    float arn0 = ar[n * 2], arn1 = ar[n * 2 + 1];
    int esub = lane >> 4;
    int c16 = lane & 15;
    float accA[4] = {0.f, 0.f, 0.f, 0.f};
    float accB[4] = {0.f, 0.f, 0.f, 0.f};
    float s0t = 0.f, s1t = 0.f;
    for (int wb = 0; wb < deg; wb += 64) {
        int cnt = deg - wb; if (cnt > 64) cnt = 64;
        float p0 = 0.f, p1 = 0.f; int colr = 0;
        if (lane < cnt) {
            colr = ecol[beg + wb + lane];
            float2 acv = ((const float2*)ac)[colr];
            float a0 = arn0 + acv.x, a1 = arn1 + acv.y;
            a0 = a0 > 0.f ? a0 : 0.2f * a0;
            a1 = a1 > 0.f ? a1 : 0.2f * a1;
            p0 = __expf(a0); p1 = __expf(a1);
            s0t += p0; s1t += p1;
        }
        int tmax = (cnt + 3) >> 2;
        for (int tt = 0; tt < tmax; tt++) {
            int i4 = tt * 4 + esub;
            int colx = __shfl(colr, i4, 64);
            float q0 = __shfl(p0, i4, 64);
            float q1 = __shfl(p1, i4, 64);
            if (i4 < cnt) {
                const uint4 u = *(const uint4*)(h0b + colx * 64 + c16 * 4);
                accA[0] += q0 * bflo(u.x); accB[0] += q1 * bfhi(u.x);
                accA[1] += q0 * bflo(u.y); accB[1] += q1 * bfhi(u.y);
                accA[2] += q0 * bflo(u.z); accB[2] += q1 * bfhi(u.z);
                accA[3] += q0 * bflo(u.w); accB[3] += q1 * bfhi(u.w);
            }
        }
    }
    float s0 = bsum64(s0t), s1 = bsum64(s1t);
    #pragma unroll
    for (int jj = 0; jj < 4; jj++) {
        accA[jj] += __shfl_xor(accA[jj], 16, 64);
        accA[jj] += __shfl_xor(accA[jj], 32, 64);
        accB[jj] += __shfl_xor(accB[jj], 16, 64);
        accB[jj] += __shfl_xor(accB[jj], 32, 64);
    }
    float si0 = deg ? 0.5f / s0 : 0.f;
    float si1 = deg ? 0.5f / s1 : 0.f;
    float pA = 0.f, pB = 0.f;
    #pragma unroll
    for (int jj = 0; jj < 4; jj++) {
        float o = si0 * accA[jj] + si1 * accB[jj];
        o = o > 0.f ? o : 0.f;   // relu
        float2 wv = ((const float2*)W1)[c16 * 4 + jj];
        pA += o * wv.x; pB += o * wv.y;
    }
    #pragma unroll
    for (int off = 1; off < 16; off <<= 1) {
        pA += __shfl_xor(pA, off, 64);
        pB += __shfl_xor(pB, off, 64);
    }
    if (lane == 0) { h1[n * 2] = pA; h1[n * 2 + 1] = pB; }
}

// ==== K5: layer 1 fused ====
__global__ __launch_bounds__(256) void k_fused1(const int* __restrict__ rowptr,
                                                const int* __restrict__ ecol,
                                                const float* __restrict__ h1,
                                                const float* __restrict__ attn1,
                                                float* __restrict__ dout) {
    int w = threadIdx.x >> 6, lane = threadIdx.x & 63;
    int n = blockIdx.x * 4 + w;
    if (n >= NNODES) return;
    int beg = rowptr[n], end = rowptr[n + 1];
    if (beg == end) { if (lane == 0) dout[n] = 0.f; return; }
    float w01 = attn1[1], w11 = attn1[3];
    float base0 = attn1[0] * h1[n * 2];
    float base1 = attn1[2] * h1[n * 2 + 1];
    float s0 = 0.f, s1 = 0.f, acc0 = 0.f, acc1 = 0.f;
    for (int i = beg + lane; i < end; i += 64) {
        int col = ecol[i];
        float2 v = ((const float2*)h1)[col];
        float a0 = base0 + w01 * v.x;
        float a1 = base1 + w11 * v.y;
        a0 = a0 > 0.f ? a0 : 0.2f * a0;
        a1 = a1 > 0.f ? a1 : 0.2f * a1;
        float p0 = __expf(a0), p1 = __expf(a1);
        s0 += p0; acc0 += p0 * v.x;
        s1 += p1; acc1 += p1 * v.y;
    }
    s0 = bsum64(s0); s1 = bsum64(s1);
    acc0 = bsum64(acc0); acc1 = bsum64(acc1);
    if (lane == 0) dout[n] = 0.5f * (acc0 / s0 + acc1 / s1);
}

extern "C" void kernel_launch(void* const* d_in, const int* in_sizes, int n_in,
                              void* d_out, int out_size, void* d_ws, size_t ws_size,
                              hipStream_t stream) {
    const float* x     = (const float*)d_in[0];
    const int*   ei    = (const int*)d_in[1];
    const float* W0    = (const float*)d_in[2];
    const float* attn0 = (const float*)d_in[3];
    const float* W1    = (const float*)d_in[4];
    const float* attn1 = (const float*)d_in[5];
    float* dout = (float*)d_out;

    float* ws = (float*)d_ws;
    float*          ar     = ws;                             // N*2
    float*          ac     = ar + NNODES * 2;                // N*2
    float*          h1     = ac + NNODES * 2;                // N*2
    unsigned*       h0b    = (unsigned*)(h1 + NNODES * 2);   // N*64
    unsigned short* Whi    = (unsigned short*)(h0b + NNODES * 64); // 128*128
    unsigned short* Wlo    = Whi + 128 * 128;                // 128*128
    int*            gcur   = (int*)(Wlo + 128 * 128);        // NBKT
    int*            rowptr = gcur + NBKT;                    // N+1
    unsigned*       stag   = (unsigned*)(rowptr + NNODES + 1); // NBKT*BKT_CAP
    int*            ecol   = (int*)(stag + NBKT * BKT_CAP);  // E

    // K1: wprep (blocks 0..63) + zero cursors (block 64)
    k_prep<<<65, 256, 0, stream>>>(W0, Whi, Wlo, gcur);
    // K2: binA (391) || l0node (782)
    k_nodeA<<<NBA + NBN, 256, 0, stream>>>(ei, gcur, stag, x, Whi, Wlo, attn0, ar, ac, h0b);
    // K3: per-bucket build of rowptr + ecol
    k_binC<<<NBKT, 256, 0, stream>>>(gcur, stag, rowptr, ecol);
    // K4: layer-0 edge work
    k_l0edge<<<(NNODES + 3) / 4, 256, 0, stream>>>(rowptr, ecol, ar, ac, h0b, W1, h1);
    // K5: layer-1
    k_fused1<<<(NNODES + 3) / 4, 256, 0, stream>>>(rowptr, ecol, h1, attn1, dout);
}